// Round 11
// baseline (798.335 us; speedup 1.0000x reference)
//
#include <hip/hip_runtime.h>
#include <hip/hip_bf16.h>

typedef float f32x4 __attribute__((ext_vector_type(4)));
typedef __bf16 bf16x8 __attribute__((ext_vector_type(8)));
typedef __bf16 bf16x4 __attribute__((ext_vector_type(4)));

#define DEVI static __device__ __forceinline__

DEVI void glds16(const void* g, void* l) {
  __builtin_amdgcn_global_load_lds((__attribute__((address_space(1))) void*)g,
                                   (__attribute__((address_space(3))) void*)l, 16, 0, 0);
}

DEVI f32x4 load4(const float* p) { return *(const f32x4*)p; }
DEVI f32x4 load4(const __bf16* p) {
  bf16x4 v = *(const bf16x4*)p;
  f32x4 o = { (float)v[0], (float)v[1], (float)v[2], (float)v[3] };
  return o;
}
DEVI void store4(float* p, f32x4 v) { *(f32x4*)p = v; }
DEVI void store4(__bf16* p, f32x4 v) {
  bf16x4 o = { (__bf16)v[0], (__bf16)v[1], (__bf16)v[2], (__bf16)v[3] };
  *(bf16x4*)p = o;
}

// ---------------- weight fp32 -> bf16 ----------------
__global__ void cvt_bf16(const float* __restrict__ in, __bf16* __restrict__ out, int n4) {
  int i = blockIdx.x * 256 + threadIdx.x;
  if (i < n4) {
    f32x4 v = *(const f32x4*)(in + (size_t)i * 4);
    store4(out + (size_t)i * 4, v);
  }
}

// ---------------- LayerNorm over C=1024, one block per token ----------------
template <typename TIN, typename TOUT>
__global__ __launch_bounds__(256) void ln_kernel(const TIN* __restrict__ x,
    const float* __restrict__ gw, const float* __restrict__ bw,
    TOUT* __restrict__ out) {
  const size_t row = blockIdx.x;
  f32x4 v = load4(x + row * 1024 + threadIdx.x * 4);
  float s = v[0] + v[1] + v[2] + v[3];
  float q = v[0]*v[0] + v[1]*v[1] + v[2]*v[2] + v[3]*v[3];
#pragma unroll
  for (int o = 32; o > 0; o >>= 1) { s += __shfl_down(s, o); q += __shfl_down(q, o); }
  __shared__ float ss[4], qq[4];
  const int w = threadIdx.x >> 6, l = threadIdx.x & 63;
  if (l == 0) { ss[w] = s; qq[w] = q; }
  __syncthreads();
  s = ss[0] + ss[1] + ss[2] + ss[3];
  q = qq[0] + qq[1] + qq[2] + qq[3];
  const float mean = s * (1.0f / 1024.0f);
  const float var = q * (1.0f / 1024.0f) - mean * mean;
  const float rstd = rsqrtf(var + 1e-5f);
  f32x4 g4 = *(const f32x4*)(gw + threadIdx.x * 4);
  f32x4 b4 = *(const f32x4*)(bw + threadIdx.x * 4);
  f32x4 o;
#pragma unroll
  for (int j = 0; j < 4; ++j) o[j] = (v[j] - mean) * rstd * g4[j] + b4[j];
  store4(out + row * 1024 + threadIdx.x * 4, o);
}

// ---------------- time-shift mix -> bf16 ----------------
template <typename TIN>
__global__ __launch_bounds__(256) void mix_kernel(const TIN* __restrict__ x,
    const float* __restrict__ tm, const float* __restrict__ cm,
    __bf16* __restrict__ out) {
  const int idx = blockIdx.x * 256 + threadIdx.x;   // over B*T*C/4
  const int t = (idx >> 8) & 2047;                   // T=2048
  const int c = (idx & 255) * 4;                     // C/4=256
  const size_t base = ((size_t)(idx >> 8) << 10) + c;
  f32x4 xv = load4(x + base);
  f32x4 xm1 = {0.f, 0.f, 0.f, 0.f}, xp1 = {0.f, 0.f, 0.f, 0.f};
  if (t > 0)    xm1 = load4(x + base - 1024);
  if (t < 2047) xp1 = load4(x + base + 1024);
  f32x4 tm4 = *(const f32x4*)(tm + c);
  f32x4 cm4 = *(const f32x4*)(cm + c);
  f32x4 xc = (c < 512) ? xm1 : xp1;
  f32x4 o;
#pragma unroll
  for (int j = 0; j < 4; ++j)
    o[j] = xv[j] * tm4[j] + xm1[j] * (1.0f - tm4[j]) + xc[j] * cm4[j];
  store4(out + base, o);
}

// ---------------- WKV chunk-parallel scan (exact regroup of reference) ----------------
__global__ __launch_bounds__(256) void wkv_part(const __bf16* __restrict__ k,
    const __bf16* __restrict__ v, const float* __restrict__ td,
    float* __restrict__ scA, float* __restrict__ scB) {
  const int gid = blockIdx.x * 256 + threadIdx.x;   // b*32768 + j*1024 + c
  const int c = gid & 1023;
  const int j = (gid >> 10) & 31;
  const int b = gid >> 15;
  const float ed = expf(-expf(td[c]));
  float A = 0.f, Bv = 0.f;
  size_t off = ((size_t)(b * 2048 + j * 64) << 10) + c;
#pragma unroll 4
  for (int i = 0; i < 64; ++i, off += 1024) {
    const float kt = (float)k[off];
    const float kv = kt * (float)v[off];
    A = ed * A + kv;
    Bv = ed * Bv + kt;
  }
  scA[gid] = A;
  scB[gid] = Bv;
}

__global__ __launch_bounds__(256) void wkv_scan(const float* __restrict__ td,
    float* __restrict__ scA, float* __restrict__ scB) {
  const int gid = blockIdx.x * 256 + threadIdx.x;   // 8192 = b*1024 + c
  const int c = gid & 1023;
  const int b = gid >> 10;
  const float edL = expf(-expf(td[c]) * 64.0f);     // ed^64
  float a = 0.f, bb = 0.f;
  size_t off = ((size_t)b << 15) + c;
  for (int j = 0; j < 32; ++j, off += 1024) {
    const float Aj = scA[off], Bj = scB[off];
    scA[off] = a;            // carry INTO chunk j
    scB[off] = bb;
    a = edL * a + Aj;
    bb = edL * bb + Bj;
  }
}

__global__ __launch_bounds__(256) void wkv_apply(const __bf16* __restrict__ k,
    const __bf16* __restrict__ v, const __bf16* __restrict__ sr,
    const float* __restrict__ td, const float* __restrict__ tf,
    const float* __restrict__ scA, const float* __restrict__ scB,
    __bf16* __restrict__ srw) {
  const int gid = blockIdx.x * 256 + threadIdx.x;
  const int c = gid & 1023;
  const int j = (gid >> 10) & 31;
  const int b = gid >> 15;
  const float ed = expf(-expf(td[c]));
  const float eu = expf(tf[c]);
  float a = scA[gid], bb = scB[gid];
  size_t off = ((size_t)(b * 2048 + j * 64) << 10) + c;
#pragma unroll 4
  for (int i = 0; i < 64; ++i, off += 1024) {
    const float kt = (float)k[off];
    const float vt = (float)v[off];
    const float kv = kt * vt;
    const float y = (a + eu * kv) / (bb + eu * kt);
    srw[off] = (__bf16)((float)sr[off] * y);
    a = ed * a + kv;
    bb = ed * bb + kt;
  }
}

// ---------------- 128x128 multi-block bf16 GEMM (m97-family, upgraded) ----------------
// out[m,n] = sum_k A[m,k]*W[n,k].  4 waves (2x2, per-wave 64x64), BK=64, dbuf
// LDS = 64 KiB -> 2 BLOCKS/CU: cross-block overlap (m114) hides barrier/drain
// stalls that killed the 256^2 mono-block variants.  128-B rows + XOR chunk
// swizzle (verified 0-conflict).  Per K-tile: VMW(0)+SBAR, 8 stage-glds (tile
// kt+1 -> buf^1), 16 ds_reads, two 16-independent-MFMA clusters gated by
// counted lgkmcnt(8)/(0).  setprio around clusters, bijective XCD swizzle.
enum { EPI_NONE = 0, EPI_EXP, EPI_SIG, EPI_RELU2, EPI_RESID, EPI_FINAL, EPI_KVR };

#define SCHED0() __builtin_amdgcn_sched_barrier(0)
#define SBAR() { __builtin_amdgcn_s_barrier(); SCHED0(); }
#define VMW0() { asm volatile("s_waitcnt vmcnt(0)" ::: "memory"); SCHED0(); }
#define LGKM(n) { asm volatile("s_waitcnt lgkmcnt(" #n ")" ::: "memory"); SCHED0(); }

template <int EPI>
__global__ __launch_bounds__(256, 2) void gemm128(
    const __bf16* __restrict__ A, const __bf16* __restrict__ W,
    void* outp, const void* res, const void* sig, const int N, const int K) {
  __shared__ __bf16 sA[2][8192];   // [buf][128 rows][64 cols], row = 128 B
  __shared__ __bf16 sB[2][8192];
  const int tid = threadIdx.x;
  const int w = tid >> 6, l = tid & 63;
  const int wr = (w >> 1) << 6, wc = (w & 1) << 6;   // 2x2 waves, 64x64 each

  // bijective XCD swizzle (all grids have nwg % 8 == 0)
  const int nwg = gridDim.x * gridDim.y;
  int wg = blockIdx.y * gridDim.x + blockIdx.x;
  wg = (wg & 7) * (nwg >> 3) + (wg >> 3);
  const int m0 = (wg / gridDim.x) << 7;
  const int n0 = (wg % gridDim.x) << 7;

  // ---- staging (linear LDS dest, pre-swizzled global source) ----
  // wave w, glds g: rows (w*32 + g*8) + (l>>3); dest chunk l&7;
  // source chunk = (l&7) ^ (row&7) = (l&7) ^ (l>>3)
  const int lr = l >> 3;
  const int lc = (l & 7) ^ lr;
  const size_t gA = (size_t)(m0 + w * 32 + lr) * K + lc * 8;
  const size_t gB = (size_t)(n0 + w * 32 + lr) * K + lc * 8;
  const int ldsD = w * 2048;   // (w*32 rows) * 64 cols

  const int NTK = K >> 6;

#define STG_A(buf, kt, g) glds16(A + gA + (size_t)(g) * 8 * K + (size_t)(kt) * 64, &sA[buf][ldsD + (g) * 512])
#define STG_B(buf, kt, g) glds16(W + gB + (size_t)(g) * 8 * K + (size_t)(kt) * 64, &sB[buf][ldsD + (g) * 512])

  // ---- fragment reads (swizzled chunk): row = base+(l&15), row&7 = l&7 ----
  const int rA = (wr + (l & 15)) * 64;
  const int rB = (wc + (l & 15)) * 64;
  const int csw = l & 7;
  const int k0 = l >> 4;    // 0..3
#define LDA(buf, mi, kk) (*(const bf16x8*)&sA[buf][rA + (mi) * 1024 + ((((kk) * 4 + k0) ^ csw) << 3)])
#define LDB(buf, ni, kk) (*(const bf16x8*)&sB[buf][rB + (ni) * 1024 + ((((kk) * 4 + k0) ^ csw) << 3)])

  f32x4 acc[4][4] = {};

  // prologue: stage tile 0 into buf 0 (8 glds per wave)
#pragma unroll
  for (int g = 0; g < 4; ++g) STG_A(0, 0, g);
#pragma unroll
  for (int g = 0; g < 4; ++g) STG_B(0, 0, g);

  for (int kt = 0; kt < NTK; ++kt) {
    const int buf = kt & 1, nb = buf ^ 1;
    const bool st = (kt + 1 < NTK);
    VMW0();                     // tile-kt staging landed (other block hides this)
    SBAR();                     // buf nb fully consumed by all waves (tile kt-1)
    if (st) {                   // stage tile kt+1
#pragma unroll
      for (int g = 0; g < 4; ++g) STG_A(nb, kt + 1, g);
#pragma unroll
      for (int g = 0; g < 4; ++g) STG_B(nb, kt + 1, g);
    }
    SCHED0();
    bf16x8 a0[4], a1[4], b0[4], b1[4];
#pragma unroll
    for (int i = 0; i < 4; ++i) a0[i] = LDA(buf, i, 0);
#pragma unroll
    for (int i = 0; i < 4; ++i) b0[i] = LDB(buf, i, 0);
    SCHED0();
#pragma unroll
    for (int i = 0; i < 4; ++i) a1[i] = LDA(buf, i, 1);
#pragma unroll
    for (int i = 0; i < 4; ++i) b1[i] = LDB(buf, i, 1);
    SCHED0();
    LGKM(8);                    // kk0 operands retired (kk1 reads may fly)
    __builtin_amdgcn_s_setprio(1);
#pragma unroll
    for (int mi = 0; mi < 4; ++mi)
#pragma unroll
      for (int ni = 0; ni < 4; ++ni)
        acc[mi][ni] = __builtin_amdgcn_mfma_f32_16x16x32_bf16(a0[mi], b0[ni], acc[mi][ni], 0, 0, 0);
    __builtin_amdgcn_s_setprio(0); SCHED0();
    LGKM(0);                    // kk1 operands retired
    __builtin_amdgcn_s_setprio(1);
#pragma unroll
    for (int mi = 0; mi < 4; ++mi)
#pragma unroll
      for (int ni = 0; ni < 4; ++ni)
        acc[mi][ni] = __builtin_amdgcn_mfma_f32_16x16x32_bf16(a1[mi], b1[ni], acc[mi][ni], 0, 0, 0);
    __builtin_amdgcn_s_setprio(0);
  }

  // ---- epilogue: C/D map col=lane&15, row=(lane>>4)*4+reg ----
  const int rl = (l >> 4) << 2, cl = l & 15;
#pragma unroll
  for (int mi = 0; mi < 4; ++mi) {
#pragma unroll
    for (int ni = 0; ni < 4; ++ni) {
#pragma unroll
      for (int e = 0; e < 4; ++e) {
        const int r = m0 + wr + mi * 16 + rl + e;
        const int cidx = n0 + wc + ni * 16 + cl;
        const size_t idx = (size_t)r * N + cidx;
        const float vacc = acc[mi][ni][e];
        if constexpr (EPI == EPI_NONE) {
          ((__bf16*)outp)[idx] = (__bf16)vacc;
        } else if constexpr (EPI == EPI_EXP) {
          ((__bf16*)outp)[idx] = (__bf16)expf(fminf(vacc, 60.0f));
        } else if constexpr (EPI == EPI_SIG) {
          ((__bf16*)outp)[idx] = (__bf16)(1.0f / (1.0f + expf(-vacc)));
        } else if constexpr (EPI == EPI_RELU2) {
          const float rv = fmaxf(vacc, 0.0f);
          ((__bf16*)outp)[idx] = (__bf16)(rv * rv);
        } else if constexpr (EPI == EPI_RESID) {
          ((__bf16*)outp)[idx] = (__bf16)(vacc + (float)((const __bf16*)res)[idx]);
        } else if constexpr (EPI == EPI_FINAL) {
          ((float*)outp)[idx] = ((const float*)res)[idx] + (float)((const __bf16*)sig)[idx] * vacc;
        } else {  // EPI_KVR: col block 0 -> k=exp(clamp), 1 -> v, 2 -> sigmoid(r)
          const int sel = cidx >> 10;               // wave-uniform (64-aligned wave cols)
          const size_t oidx = (size_t)r * 1024 + (cidx & 1023);
          if (sel == 0)      ((__bf16*)outp)[oidx] = (__bf16)expf(fminf(vacc, 60.0f));
          else if (sel == 1) ((__bf16*)const_cast<void*>(res))[oidx] = (__bf16)vacc;
          else               ((__bf16*)const_cast<void*>(sig))[oidx] = (__bf16)(1.0f / (1.0f + expf(-vacc)));
        }
      }
    }
  }
}

// ---------------- launch ----------------
extern "C" void kernel_launch(void* const* d_in, const int* in_sizes, int n_in,
                              void* d_out, int out_size, void* d_ws, size_t ws_size,
                              hipStream_t stream) {
  (void)in_sizes; (void)n_in; (void)out_size;
  const float* x    = (const float*)d_in[0];
  const float* ln1g = (const float*)d_in[1];
  const float* ln1b = (const float*)d_in[2];
  const float* ln2g = (const float*)d_in[3];
  const float* ln2b = (const float*)d_in[4];
  const float* atm  = (const float*)d_in[5];
  const float* acm  = (const float*)d_in[6];
  const float* td   = (const float*)d_in[7];
  const float* tf   = (const float*)d_in[8];
  const float* Wk   = (const float*)d_in[9];
  const float* Wv   = (const float*)d_in[10];
  const float* Wr   = (const float*)d_in[11];
  const float* Wo   = (const float*)d_in[12];
  const float* ftm  = (const float*)d_in[13];
  const float* fcm  = (const float*)d_in[14];
  const float* Fk   = (const float*)d_in[15];
  const float* Fv   = (const float*)d_in[16];
  const float* Fr   = (const float*)d_in[17];

  constexpr size_t C = 1024, T = 2048, Bs = 8, H = 4096;
  constexpr size_t NT = Bs * T;        // 16384 tokens
  constexpr size_t NTC = NT * C;       // 16M elems
  constexpr size_t CC = C * C;
  constexpr size_t CH = C * H;

  // ---- workspace layout ----
  char* p = (char*)d_ws;
  auto takeb = [&](size_t elems) { __bf16* q = (__bf16*)p; p += elems * 2; return q; };
  __bf16* wKVR = takeb(3 * CC);   // [Wk; Wv; Wr] rows stacked -> (3072, 1024)
  __bf16* wWo  = takeb(CC);
  __bf16* wFk  = takeb(CH);
  __bf16* wFv  = takeb(CH);
  __bf16* wFr  = takeb(CC);
  __bf16* Ab   = takeb(NTC);      // x1 -> x2 (in-place residual)
  __bf16* Bb   = takeb(NTC);      // xm -> srw -> sr2
  __bf16* Db   = takeb(NTC);      // v  -> xm2
  float* scA = (float*)p; p += Bs * 32 * C * 4;   // wkv carries (b,j,c)
  float* scB = (float*)p; p += Bs * 32 * C * 4;
  __bf16* kk = (__bf16*)p;        // k lives here too (dead before Fk writes kk)
  const size_t used = (size_t)(p - (char*)d_ws);
  const size_t kkcap = ws_size > used ? ws_size - used : 0;
  int chunks = 4;                                   // 32 MiB kk
  if (kkcap >= NT * H * 2)          chunks = 1;     // 128 MiB kk
  else if (kkcap >= NT * H)         chunks = 2;     // 64 MiB kk
  __bf16* Cb = kk;                 // k buffer (32 MiB) aliases kk region
  __bf16* sr  = (__bf16*)d_out;    // sigmoid(r) borrows d_out until ln2 overwrites it
  float*  x3  = (float*)d_out;

  auto cvt = [&](const float* src, size_t n, __bf16* dst) {
    const int n4 = (int)(n / 4);
    cvt_bf16<<<dim3((n4 + 255) / 256), dim3(256), 0, stream>>>(src, dst, n4);
  };
  cvt(Wk, CC, wKVR); cvt(Wv, CC, wKVR + CC); cvt(Wr, CC, wKVR + 2 * CC);
  cvt(Wo, CC, wWo); cvt(Fk, CH, wFk); cvt(Fv, CH, wFv); cvt(Fr, CC, wFr);

  const dim3 blk(256);

  // x1 = ln1(x)            [Ab]
  ln_kernel<float, __bf16><<<dim3((unsigned)NT), blk, 0, stream>>>(x, ln1g, ln1b, Ab);
  // xm = mix(x1)           [Bb]
  mix_kernel<__bf16><<<dim3((unsigned)(NTC / 1024)), blk, 0, stream>>>(Ab, atm, acm, Bb);
  // fused: k=exp(min(.,60)) [Cb], v [Db], sigmoid(r) [sr]
  gemm128<EPI_KVR><<<dim3(24, 128), blk, 0, stream>>>(Bb, wKVR, Cb, Db, sr, 3072, 1024);
  // wkv: chunk partials -> carry scan -> apply (srw = sigmoid(r)*y into Bb)
  wkv_part<<<dim3(1024), blk, 0, stream>>>(Cb, Db, td, scA, scB);
  wkv_scan<<<dim3(32), blk, 0, stream>>>(td, scA, scB);
  wkv_apply<<<dim3(1024), blk, 0, stream>>>(Cb, Db, sr, td, tf, scA, scB, Bb);
  // x2 = x1 + srw@Wo^T     [Ab in-place]
  gemm128<EPI_RESID><<<dim3(8, 128), blk, 0, stream>>>(Bb, wWo, Ab, Ab, nullptr, 1024, 1024);
  // x3 = ln2(x2)           [d_out, fp32]
  ln_kernel<__bf16, float><<<dim3((unsigned)NT), blk, 0, stream>>>(Ab, ln2g, ln2b, x3);
  // xm2 = mix(x3)          [Db]
  mix_kernel<float><<<dim3((unsigned)(NTC / 1024)), blk, 0, stream>>>(x3, ftm, fcm, Db);
  // sr2 = sigmoid(xm2@Fr^T) [Bb]
  gemm128<EPI_SIG><<<dim3(8, 128), blk, 0, stream>>>(Db, wFr, Bb, nullptr, nullptr, 1024, 1024);
  // FFN: kk = relu(xm2@Fk^T)^2 [kk], out = x3 + sr2 * (kk@Fv^T)  (chunked if ws small)
  const size_t Mc = NT / chunks;
  for (int ch = 0; ch < chunks; ++ch) {
    const size_t ro = (size_t)ch * Mc;
    gemm128<EPI_RELU2><<<dim3(32, (unsigned)(Mc / 128)), blk, 0, stream>>>(
        Db + ro * C, wFk, kk, nullptr, nullptr, 4096, 1024);
    gemm128<EPI_FINAL><<<dim3(8, (unsigned)(Mc / 128)), blk, 0, stream>>>(
        kk, wFv, (float*)d_out + ro * C, (const float*)d_out + ro * C,
        Bb + ro * C, 1024, 4096);
  }
}

// Round 12
// 786.275 us; speedup vs baseline: 1.0153x; 1.0153x over previous
//
#include <hip/hip_runtime.h>
#include <hip/hip_bf16.h>

typedef float f32x4 __attribute__((ext_vector_type(4)));
typedef __bf16 bf16x8 __attribute__((ext_vector_type(8)));
typedef __bf16 bf16x4 __attribute__((ext_vector_type(4)));

#define DEVI static __device__ __forceinline__

DEVI void glds16(const void* g, void* l) {
  __builtin_amdgcn_global_load_lds((__attribute__((address_space(1))) void*)g,
                                   (__attribute__((address_space(3))) void*)l, 16, 0, 0);
}

DEVI f32x4 load4(const float* p) { return *(const f32x4*)p; }
DEVI f32x4 load4(const __bf16* p) {
  bf16x4 v = *(const bf16x4*)p;
  f32x4 o = { (float)v[0], (float)v[1], (float)v[2], (float)v[3] };
  return o;
}
DEVI void store4(float* p, f32x4 v) { *(f32x4*)p = v; }
DEVI void store4(__bf16* p, f32x4 v) {
  bf16x4 o = { (__bf16)v[0], (__bf16)v[1], (__bf16)v[2], (__bf16)v[3] };
  *(bf16x4*)p = o;
}

constexpr size_t C = 1024, T = 2048, Bs = 8, H = 4096;
constexpr size_t NT = Bs * T;        // 16384 tokens
constexpr size_t NTC = NT * C;       // 16M elems
constexpr size_t CC = C * C;
constexpr size_t CH = C * H;

// ---------------- all weights fp32 -> bf16, one launch ----------------
// dst regions contiguous: [Wk|Wv|Wr|Wo|Fk|Fv|Fr] (elements: CC,CC,CC,CC,CH,CH,CC)
__global__ __launch_bounds__(256) void cvt_all(
    const float* __restrict__ Wk, const float* __restrict__ Wv,
    const float* __restrict__ Wr, const float* __restrict__ Wo,
    const float* __restrict__ Fk, const float* __restrict__ Fv,
    const float* __restrict__ Fr, __bf16* __restrict__ out) {
  const size_t e = ((size_t)blockIdx.x * 256 + threadIdx.x) * 4;
  const float* src; size_t rel;
  if      (e < CC)          { src = Wk; rel = e; }
  else if (e < 2 * CC)      { src = Wv; rel = e - CC; }
  else if (e < 3 * CC)      { src = Wr; rel = e - 2 * CC; }
  else if (e < 4 * CC)      { src = Wo; rel = e - 3 * CC; }
  else if (e < 4 * CC + CH) { src = Fk; rel = e - 4 * CC; }
  else if (e < 4 * CC + 2 * CH) { src = Fv; rel = e - 4 * CC - CH; }
  else                      { src = Fr; rel = e - 4 * CC - 2 * CH; }
  f32x4 v = *(const f32x4*)(src + rel);
  store4(out + e, v);
}

// ---------------- LayerNorm over C=1024, one block per token ----------------
template <typename TIN, typename TOUT>
__global__ __launch_bounds__(256) void ln_kernel(const TIN* __restrict__ x,
    const float* __restrict__ gw, const float* __restrict__ bw,
    TOUT* __restrict__ out) {
  const size_t row = blockIdx.x;
  f32x4 v = load4(x + row * 1024 + threadIdx.x * 4);
  float s = v[0] + v[1] + v[2] + v[3];
  float q = v[0]*v[0] + v[1]*v[1] + v[2]*v[2] + v[3]*v[3];
#pragma unroll
  for (int o = 32; o > 0; o >>= 1) { s += __shfl_down(s, o); q += __shfl_down(q, o); }
  __shared__ float ss[4], qq[4];
  const int w = threadIdx.x >> 6, l = threadIdx.x & 63;
  if (l == 0) { ss[w] = s; qq[w] = q; }
  __syncthreads();
  s = ss[0] + ss[1] + ss[2] + ss[3];
  q = qq[0] + qq[1] + qq[2] + qq[3];
  const float mean = s * (1.0f / 1024.0f);
  const float var = q * (1.0f / 1024.0f) - mean * mean;
  const float rstd = rsqrtf(var + 1e-5f);
  f32x4 g4 = *(const f32x4*)(gw + threadIdx.x * 4);
  f32x4 b4 = *(const f32x4*)(bw + threadIdx.x * 4);
  f32x4 o;
#pragma unroll
  for (int j = 0; j < 4; ++j) o[j] = (v[j] - mean) * rstd * g4[j] + b4[j];
  store4(out + row * 1024 + threadIdx.x * 4, o);
}

// ---------------- time-shift mix -> bf16 ----------------
template <typename TIN>
__global__ __launch_bounds__(256) void mix_kernel(const TIN* __restrict__ x,
    const float* __restrict__ tm, const float* __restrict__ cm,
    __bf16* __restrict__ out) {
  const int idx = blockIdx.x * 256 + threadIdx.x;   // over B*T*C/4
  const int t = (idx >> 8) & 2047;                   // T=2048
  const int c = (idx & 255) * 4;                     // C/4=256
  const size_t base = ((size_t)(idx >> 8) << 10) + c;
  f32x4 xv = load4(x + base);
  f32x4 xm1 = {0.f, 0.f, 0.f, 0.f}, xp1 = {0.f, 0.f, 0.f, 0.f};
  if (t > 0)    xm1 = load4(x + base - 1024);
  if (t < 2047) xp1 = load4(x + base + 1024);
  f32x4 tm4 = *(const f32x4*)(tm + c);
  f32x4 cm4 = *(const f32x4*)(cm + c);
  f32x4 xc = (c < 512) ? xm1 : xp1;
  f32x4 o;
#pragma unroll
  for (int j = 0; j < 4; ++j)
    o[j] = xv[j] * tm4[j] + xm1[j] * (1.0f - tm4[j]) + xc[j] * cm4[j];
  store4(out + base, o);
}

// ---------------- WKV chunk-parallel scan, x4 vectorized ----------------
// Exact regroup of reference recurrence; each thread owns 4 channels.
__global__ __launch_bounds__(256) void wkv_part(const __bf16* __restrict__ k,
    const __bf16* __restrict__ v, const float* __restrict__ td,
    float* __restrict__ scA, float* __restrict__ scB) {
  const int gid = blockIdx.x * 256 + threadIdx.x;   // b*8192 + j*256 + c4
  const int c = (gid & 255) * 4;
  const int j = (gid >> 8) & 31;
  const int b = gid >> 13;
  float ed[4], A[4] = {}, Bv[4] = {};
#pragma unroll
  for (int q = 0; q < 4; ++q) ed[q] = expf(-expf(td[c + q]));
  size_t off = ((size_t)(b * 2048 + j * 64) << 10) + c;
  for (int i = 0; i < 64; ++i, off += 1024) {
    bf16x4 k4 = *(const bf16x4*)(k + off);
    bf16x4 v4 = *(const bf16x4*)(v + off);
#pragma unroll
    for (int q = 0; q < 4; ++q) {
      const float kt = (float)k4[q];
      A[q] = ed[q] * A[q] + kt * (float)v4[q];
      Bv[q] = ed[q] * Bv[q] + kt;
    }
  }
  const size_t sidx = (((size_t)b * 32 + j) << 10) + c;
  f32x4 oA = { A[0], A[1], A[2], A[3] };
  f32x4 oB = { Bv[0], Bv[1], Bv[2], Bv[3] };
  *(f32x4*)(scA + sidx) = oA;
  *(f32x4*)(scB + sidx) = oB;
}

__global__ __launch_bounds__(256) void wkv_scan(const float* __restrict__ td,
    float* __restrict__ scA, float* __restrict__ scB) {
  const int gid = blockIdx.x * 256 + threadIdx.x;   // 2048 = b*256 + c4
  const int c = (gid & 255) * 4;
  const int b = gid >> 8;
  float edL[4], a[4] = {}, bb[4] = {};
#pragma unroll
  for (int q = 0; q < 4; ++q) edL[q] = expf(-expf(td[c + q]) * 64.0f);
  size_t off = ((size_t)b << 15) + c;
  for (int j = 0; j < 32; ++j, off += 1024) {
    f32x4 Aj = *(const f32x4*)(scA + off);
    f32x4 Bj = *(const f32x4*)(scB + off);
    f32x4 ca = { a[0], a[1], a[2], a[3] };
    f32x4 cb = { bb[0], bb[1], bb[2], bb[3] };
    *(f32x4*)(scA + off) = ca;       // carry INTO chunk j
    *(f32x4*)(scB + off) = cb;
#pragma unroll
    for (int q = 0; q < 4; ++q) {
      a[q] = edL[q] * a[q] + Aj[q];
      bb[q] = edL[q] * bb[q] + Bj[q];
    }
  }
}

__global__ __launch_bounds__(256) void wkv_apply(const __bf16* __restrict__ k,
    const __bf16* __restrict__ v, const __bf16* __restrict__ sr,
    const float* __restrict__ td, const float* __restrict__ tf,
    const float* __restrict__ scA, const float* __restrict__ scB,
    __bf16* __restrict__ srw) {
  const int gid = blockIdx.x * 256 + threadIdx.x;   // b*8192 + j*256 + c4
  const int c = (gid & 255) * 4;
  const int j = (gid >> 8) & 31;
  const int b = gid >> 13;
  float ed[4], eu[4], a[4], bb[4];
#pragma unroll
  for (int q = 0; q < 4; ++q) { ed[q] = expf(-expf(td[c + q])); eu[q] = expf(tf[c + q]); }
  const size_t sidx = (((size_t)b * 32 + j) << 10) + c;
  f32x4 ca = *(const f32x4*)(scA + sidx);
  f32x4 cb = *(const f32x4*)(scB + sidx);
#pragma unroll
  for (int q = 0; q < 4; ++q) { a[q] = ca[q]; bb[q] = cb[q]; }
  size_t off = ((size_t)(b * 2048 + j * 64) << 10) + c;
  for (int i = 0; i < 64; ++i, off += 1024) {
    bf16x4 k4 = *(const bf16x4*)(k + off);
    bf16x4 v4 = *(const bf16x4*)(v + off);
    bf16x4 s4 = *(const bf16x4*)(sr + off);
    bf16x4 o4;
#pragma unroll
    for (int q = 0; q < 4; ++q) {
      const float kt = (float)k4[q];
      const float kv = kt * (float)v4[q];
      const float y = (a[q] + eu[q] * kv) / (bb[q] + eu[q] * kt);
      o4[q] = (__bf16)((float)s4[q] * y);
      a[q] = ed[q] * a[q] + kv;
      bb[q] = ed[q] * bb[q] + kt;
    }
    *(bf16x4*)(srw + off) = o4;
  }
}

// ---------------- 128x128 m97-style multi-block bf16 GEMM ----------------
// out[m,n] = sum_k A[m,k]*W[n,k].  4 waves (2x2, per-wave 64x64), BK=64,
// SINGLE-buffered LDS = 32 KiB -> ~3 blocks/CU; cross-block overlap (m114)
// hides the per-tile drain.  128-B rows + XOR chunk swizzle (verified
// 0-conflict, R11).  PURE COMPILER SCHEDULING: no inline-asm waitcnt, no
// sched_barrier, no setprio (m141: order-pinning defeats the scheduler;
// m97: this exact pattern = 37% MfmaUtil).  Bijective XCD swizzle.
enum { EPI_NONE = 0, EPI_EXP, EPI_SIG, EPI_RELU2, EPI_RESID, EPI_FINAL, EPI_KVR };

template <int EPI>
__global__ __launch_bounds__(256) void gemm128(
    const __bf16* __restrict__ A, const __bf16* __restrict__ W,
    void* outp, const void* res, const void* sig, const int N, const int K) {
  __shared__ __bf16 sA[8192];   // [128 rows][64 cols], row = 128 B
  __shared__ __bf16 sB[8192];
  const int tid = threadIdx.x;
  const int w = tid >> 6, l = tid & 63;
  const int wr = (w >> 1) << 6, wc = (w & 1) << 6;   // 2x2 waves, 64x64 each

  // bijective XCD swizzle (all grids have nwg % 8 == 0)
  const int nwg = gridDim.x * gridDim.y;
  int wg = blockIdx.y * gridDim.x + blockIdx.x;
  wg = (wg & 7) * (nwg >> 3) + (wg >> 3);
  const int m0 = (wg / gridDim.x) << 7;
  const int n0 = (wg % gridDim.x) << 7;

  // ---- staging (linear LDS dest, pre-swizzled global source) ----
  // wave w, glds g: rows (w*32 + g*8) + (l>>3); dest chunk l&7;
  // source chunk = (l&7) ^ (row&7) = (l&7) ^ (l>>3)
  const int lr = l >> 3;
  const int lc = (l & 7) ^ lr;
  const size_t gA = (size_t)(m0 + w * 32 + lr) * K + lc * 8;
  const size_t gB = (size_t)(n0 + w * 32 + lr) * K + lc * 8;
  const int ldsD = w * 2048;   // (w*32 rows) * 64 cols

  const int NTK = K >> 6;

#define STG_A(kt, g) glds16(A + gA + (size_t)(g) * 8 * K + (size_t)(kt) * 64, &sA[ldsD + (g) * 512])
#define STG_B(kt, g) glds16(W + gB + (size_t)(g) * 8 * K + (size_t)(kt) * 64, &sB[ldsD + (g) * 512])

  // ---- fragment reads (swizzled chunk): row = base+(l&15), row&7 = l&7 ----
  const int rA = (wr + (l & 15)) * 64;
  const int rB = (wc + (l & 15)) * 64;
  const int csw = l & 7;
  const int k0 = l >> 4;    // 0..3
#define LDA(mi, kk) (*(const bf16x8*)&sA[rA + (mi) * 1024 + ((((kk) * 4 + k0) ^ csw) << 3)])
#define LDB(ni, kk) (*(const bf16x8*)&sB[rB + (ni) * 1024 + ((((kk) * 4 + k0) ^ csw) << 3)])

  f32x4 acc[4][4] = {};

  for (int kt = 0; kt < NTK; ++kt) {
    if (kt) __syncthreads();    // all waves done reading previous tile
#pragma unroll
    for (int g = 0; g < 4; ++g) STG_A(kt, g);
#pragma unroll
    for (int g = 0; g < 4; ++g) STG_B(kt, g);
    __syncthreads();            // staging landed (compiler drains vmcnt)
    bf16x8 a0[4], a1[4], b0[4], b1[4];
#pragma unroll
    for (int i = 0; i < 4; ++i) a0[i] = LDA(i, 0);
#pragma unroll
    for (int i = 0; i < 4; ++i) b0[i] = LDB(i, 0);
#pragma unroll
    for (int i = 0; i < 4; ++i) a1[i] = LDA(i, 1);
#pragma unroll
    for (int i = 0; i < 4; ++i) b1[i] = LDB(i, 1);
#pragma unroll
    for (int mi = 0; mi < 4; ++mi)
#pragma unroll
      for (int ni = 0; ni < 4; ++ni)
        acc[mi][ni] = __builtin_amdgcn_mfma_f32_16x16x32_bf16(a0[mi], b0[ni], acc[mi][ni], 0, 0, 0);
#pragma unroll
    for (int mi = 0; mi < 4; ++mi)
#pragma unroll
      for (int ni = 0; ni < 4; ++ni)
        acc[mi][ni] = __builtin_amdgcn_mfma_f32_16x16x32_bf16(a1[mi], b1[ni], acc[mi][ni], 0, 0, 0);
  }

  // ---- epilogue: C/D map col=lane&15, row=(lane>>4)*4+reg ----
  const int rl = (l >> 4) << 2, cl = l & 15;
#pragma unroll
  for (int mi = 0; mi < 4; ++mi) {
#pragma unroll
    for (int ni = 0; ni < 4; ++ni) {
#pragma unroll
      for (int e = 0; e < 4; ++e) {
        const int r = m0 + wr + mi * 16 + rl + e;
        const int cidx = n0 + wc + ni * 16 + cl;
        const size_t idx = (size_t)r * N + cidx;
        const float vacc = acc[mi][ni][e];
        if constexpr (EPI == EPI_NONE) {
          ((__bf16*)outp)[idx] = (__bf16)vacc;
        } else if constexpr (EPI == EPI_EXP) {
          ((__bf16*)outp)[idx] = (__bf16)expf(fminf(vacc, 60.0f));
        } else if constexpr (EPI == EPI_SIG) {
          ((__bf16*)outp)[idx] = (__bf16)(1.0f / (1.0f + expf(-vacc)));
        } else if constexpr (EPI == EPI_RELU2) {
          const float rv = fmaxf(vacc, 0.0f);
          ((__bf16*)outp)[idx] = (__bf16)(rv * rv);
        } else if constexpr (EPI == EPI_RESID) {
          ((__bf16*)outp)[idx] = (__bf16)(vacc + (float)((const __bf16*)res)[idx]);
        } else if constexpr (EPI == EPI_FINAL) {
          ((float*)outp)[idx] = ((const float*)res)[idx] + (float)((const __bf16*)sig)[idx] * vacc;
        } else {  // EPI_KVR: col block 0 -> k=exp(clamp), 1 -> v, 2 -> sigmoid(r)
          const int sel = cidx >> 10;               // wave-uniform (64-aligned wave cols)
          const size_t oidx = (size_t)r * 1024 + (cidx & 1023);
          if (sel == 0)      ((__bf16*)outp)[oidx] = (__bf16)expf(fminf(vacc, 60.0f));
          else if (sel == 1) ((__bf16*)const_cast<void*>(res))[oidx] = (__bf16)vacc;
          else               ((__bf16*)const_cast<void*>(sig))[oidx] = (__bf16)(1.0f / (1.0f + expf(-vacc)));
        }
      }
    }
  }
}

// ---------------- launch ----------------
extern "C" void kernel_launch(void* const* d_in, const int* in_sizes, int n_in,
                              void* d_out, int out_size, void* d_ws, size_t ws_size,
                              hipStream_t stream) {
  (void)in_sizes; (void)n_in; (void)out_size;
  const float* x    = (const float*)d_in[0];
  const float* ln1g = (const float*)d_in[1];
  const float* ln1b = (const float*)d_in[2];
  const float* ln2g = (const float*)d_in[3];
  const float* ln2b = (const float*)d_in[4];
  const float* atm  = (const float*)d_in[5];
  const float* acm  = (const float*)d_in[6];
  const float* td   = (const float*)d_in[7];
  const float* tf   = (const float*)d_in[8];
  const float* Wk   = (const float*)d_in[9];
  const float* Wv   = (const float*)d_in[10];
  const float* Wr   = (const float*)d_in[11];
  const float* Wo   = (const float*)d_in[12];
  const float* ftm  = (const float*)d_in[13];
  const float* fcm  = (const float*)d_in[14];
  const float* Fk   = (const float*)d_in[15];
  const float* Fv   = (const float*)d_in[16];
  const float* Fr   = (const float*)d_in[17];

  // ---- workspace layout ----
  char* p = (char*)d_ws;
  auto takeb = [&](size_t elems) { __bf16* q = (__bf16*)p; p += elems * 2; return q; };
  __bf16* wKVR = takeb(3 * CC);   // [Wk; Wv; Wr] rows stacked -> (3072, 1024)
  __bf16* wWo  = takeb(CC);
  __bf16* wFk  = takeb(CH);
  __bf16* wFv  = takeb(CH);
  __bf16* wFr  = takeb(CC);
  __bf16* Ab   = takeb(NTC);      // x1 -> x2 (in-place residual)
  __bf16* Bb   = takeb(NTC);      // xm -> srw -> sr2
  __bf16* Db   = takeb(NTC);      // v  -> xm2
  float* scA = (float*)p; p += Bs * 32 * C * 4;   // wkv carries (b,j,c)
  float* scB = (float*)p; p += Bs * 32 * C * 4;
  __bf16* kk = (__bf16*)p;        // k lives here too (dead before Fk writes kk)
  const size_t used = (size_t)(p - (char*)d_ws);
  const size_t kkcap = ws_size > used ? ws_size - used : 0;
  int chunks = 4;                                   // 32 MiB kk
  if (kkcap >= NT * H * 2)          chunks = 1;     // 128 MiB kk
  else if (kkcap >= NT * H)         chunks = 2;     // 64 MiB kk
  __bf16* Cb = kk;                 // k buffer (32 MiB) aliases kk region
  __bf16* sr  = (__bf16*)d_out;    // sigmoid(r) borrows d_out until ln2 overwrites it
  float*  x3  = (float*)d_out;

  const dim3 blk(256);

  // weights -> bf16 (one launch; dst regions contiguous)
  cvt_all<<<dim3((unsigned)((5 * CC + 2 * CH) / 4 / 256)), blk, 0, stream>>>(
      Wk, Wv, Wr, Wo, Fk, Fv, Fr, wKVR);

  // x1 = ln1(x)            [Ab]
  ln_kernel<float, __bf16><<<dim3((unsigned)NT), blk, 0, stream>>>(x, ln1g, ln1b, Ab);
  // xm = mix(x1)           [Bb]
  mix_kernel<__bf16><<<dim3((unsigned)(NTC / 1024)), blk, 0, stream>>>(Ab, atm, acm, Bb);
  // fused: k=exp(min(.,60)) [Cb], v [Db], sigmoid(r) [sr]
  gemm128<EPI_KVR><<<dim3(24, 128), blk, 0, stream>>>(Bb, wKVR, Cb, Db, sr, 3072, 1024);
  // wkv: chunk partials -> carry scan -> apply (srw = sigmoid(r)*y into Bb)
  wkv_part<<<dim3(256), blk, 0, stream>>>(Cb, Db, td, scA, scB);
  wkv_scan<<<dim3(8), blk, 0, stream>>>(td, scA, scB);
  wkv_apply<<<dim3(256), blk, 0, stream>>>(Cb, Db, sr, td, tf, scA, scB, Bb);
  // x2 = x1 + srw@Wo^T     [Ab in-place]
  gemm128<EPI_RESID><<<dim3(8, 128), blk, 0, stream>>>(Bb, wWo, Ab, Ab, nullptr, 1024, 1024);
  // x3 = ln2(x2)           [d_out, fp32]
  ln_kernel<__bf16, float><<<dim3((unsigned)NT), blk, 0, stream>>>(Ab, ln2g, ln2b, x3);
  // xm2 = mix(x3)          [Db]
  mix_kernel<float><<<dim3((unsigned)(NTC / 1024)), blk, 0, stream>>>(x3, ftm, fcm, Db);
  // sr2 = sigmoid(xm2@Fr^T) [Bb]
  gemm128<EPI_SIG><<<dim3(8, 128), blk, 0, stream>>>(Db, wFr, Bb, nullptr, nullptr, 1024, 1024);
  // FFN: kk = relu(xm2@Fk^T)^2 [kk], out = x3 + sr2 * (kk@Fv^T)  (chunked if ws small)
  const size_t Mc = NT / chunks;
  for (int ch = 0; ch < chunks; ++ch) {
    const size_t ro = (size_t)ch * Mc;
    gemm128<EPI_RELU2><<<dim3(32, (unsigned)(Mc / 128)), blk, 0, stream>>>(
        Db + ro * C, wFk, kk, nullptr, nullptr, 4096, 1024);
    gemm128<EPI_FINAL><<<dim3(8, (unsigned)(Mc / 128)), blk, 0, stream>>>(
        kk, wFv, (float*)d_out + ro * C, (const float*)d_out + ro * C,
        Bb + ro * C, 1024, 4096);
  }
}

// Round 13
// 736.265 us; speedup vs baseline: 1.0843x; 1.0679x over previous
//
#include <hip/hip_runtime.h>
#include <hip/hip_bf16.h>

typedef float f32x4 __attribute__((ext_vector_type(4)));
typedef __bf16 bf16x8 __attribute__((ext_vector_type(8)));
typedef __bf16 bf16x4 __attribute__((ext_vector_type(4)));

#define DEVI static __device__ __forceinline__

DEVI void glds16(const void* g, void* l) {
  __builtin_amdgcn_global_load_lds((__attribute__((address_space(1))) void*)g,
                                   (__attribute__((address_space(3))) void*)l, 16, 0, 0);
}

DEVI f32x4 load4(const float* p) { return *(const f32x4*)p; }
DEVI f32x4 load4(const __bf16* p) {
  bf16x4 v = *(const bf16x4*)p;
  f32x4 o = { (float)v[0], (float)v[1], (float)v[2], (float)v[3] };
  return o;
}
DEVI void store4(float* p, f32x4 v) { *(f32x4*)p = v; }
DEVI void store4(__bf16* p, f32x4 v) {
  bf16x4 o = { (__bf16)v[0], (__bf16)v[1], (__bf16)v[2], (__bf16)v[3] };
  *(bf16x4*)p = o;
}

constexpr size_t C = 1024, T = 2048, Bs = 8, H = 4096;
constexpr size_t NT = Bs * T;        // 16384 tokens
constexpr size_t NTC = NT * C;       // 16M elems
constexpr size_t CC = C * C;
constexpr size_t CH = C * H;

// ---------------- all weights fp32 -> bf16, one launch ----------------
// dst region order: [Wk|Wv|Wr | Wo | Fk|Fr | Fv]  (Fk+Fr contiguous = fused FFN B)
__global__ __launch_bounds__(256) void cvt_all(
    const float* __restrict__ Wk, const float* __restrict__ Wv,
    const float* __restrict__ Wr, const float* __restrict__ Wo,
    const float* __restrict__ Fk, const float* __restrict__ Fr,
    const float* __restrict__ Fv, __bf16* __restrict__ out) {
  const size_t e = ((size_t)blockIdx.x * 256 + threadIdx.x) * 4;
  const float* src; size_t rel;
  if      (e < CC)                   { src = Wk; rel = e; }
  else if (e < 2 * CC)               { src = Wv; rel = e - CC; }
  else if (e < 3 * CC)               { src = Wr; rel = e - 2 * CC; }
  else if (e < 4 * CC)               { src = Wo; rel = e - 3 * CC; }
  else if (e < 4 * CC + CH)          { src = Fk; rel = e - 4 * CC; }
  else if (e < 5 * CC + CH)          { src = Fr; rel = e - 4 * CC - CH; }
  else                               { src = Fv; rel = e - 5 * CC - CH; }
  f32x4 v = *(const f32x4*)(src + rel);
  store4(out + e, v);
}

// ---------------- LayerNorm over C=1024, one block per token ----------------
template <typename TIN, typename TOUT>
__global__ __launch_bounds__(256) void ln_kernel(const TIN* __restrict__ x,
    const float* __restrict__ gw, const float* __restrict__ bw,
    TOUT* __restrict__ out) {
  const size_t row = blockIdx.x;
  f32x4 v = load4(x + row * 1024 + threadIdx.x * 4);
  float s = v[0] + v[1] + v[2] + v[3];
  float q = v[0]*v[0] + v[1]*v[1] + v[2]*v[2] + v[3]*v[3];
#pragma unroll
  for (int o = 32; o > 0; o >>= 1) { s += __shfl_down(s, o); q += __shfl_down(q, o); }
  __shared__ float ss[4], qq[4];
  const int w = threadIdx.x >> 6, l = threadIdx.x & 63;
  if (l == 0) { ss[w] = s; qq[w] = q; }
  __syncthreads();
  s = ss[0] + ss[1] + ss[2] + ss[3];
  q = qq[0] + qq[1] + qq[2] + qq[3];
  const float mean = s * (1.0f / 1024.0f);
  const float var = q * (1.0f / 1024.0f) - mean * mean;
  const float rstd = rsqrtf(var + 1e-5f);
  f32x4 g4 = *(const f32x4*)(gw + threadIdx.x * 4);
  f32x4 b4 = *(const f32x4*)(bw + threadIdx.x * 4);
  f32x4 o;
#pragma unroll
  for (int j = 0; j < 4; ++j) o[j] = (v[j] - mean) * rstd * g4[j] + b4[j];
  store4(out + row * 1024 + threadIdx.x * 4, o);
}

// ---------------- time-shift mix -> bf16 ----------------
template <typename TIN>
__global__ __launch_bounds__(256) void mix_kernel(const TIN* __restrict__ x,
    const float* __restrict__ tm, const float* __restrict__ cm,
    __bf16* __restrict__ out) {
  const int idx = blockIdx.x * 256 + threadIdx.x;   // over B*T*C/4
  const int t = (idx >> 8) & 2047;                   // T=2048
  const int c = (idx & 255) * 4;                     // C/4=256
  const size_t base = ((size_t)(idx >> 8) << 10) + c;
  f32x4 xv = load4(x + base);
  f32x4 xm1 = {0.f, 0.f, 0.f, 0.f}, xp1 = {0.f, 0.f, 0.f, 0.f};
  if (t > 0)    xm1 = load4(x + base - 1024);
  if (t < 2047) xp1 = load4(x + base + 1024);
  f32x4 tm4 = *(const f32x4*)(tm + c);
  f32x4 cm4 = *(const f32x4*)(cm + c);
  f32x4 xc = (c < 512) ? xm1 : xp1;
  f32x4 o;
#pragma unroll
  for (int j = 0; j < 4; ++j)
    o[j] = xv[j] * tm4[j] + xm1[j] * (1.0f - tm4[j]) + xc[j] * cm4[j];
  store4(out + base, o);
}

// ---------------- WKV chunk-parallel scan, x4 vectorized (exact regroup) ----------------
__global__ __launch_bounds__(256) void wkv_part(const __bf16* __restrict__ k,
    const __bf16* __restrict__ v, const float* __restrict__ td,
    float* __restrict__ scA, float* __restrict__ scB) {
  const int gid = blockIdx.x * 256 + threadIdx.x;   // b*8192 + j*256 + c4
  const int c = (gid & 255) * 4;
  const int j = (gid >> 8) & 31;
  const int b = gid >> 13;
  float ed[4], A[4] = {}, Bv[4] = {};
#pragma unroll
  for (int q = 0; q < 4; ++q) ed[q] = expf(-expf(td[c + q]));
  size_t off = ((size_t)(b * 2048 + j * 64) << 10) + c;
  for (int i = 0; i < 64; ++i, off += 1024) {
    bf16x4 k4 = *(const bf16x4*)(k + off);
    bf16x4 v4 = *(const bf16x4*)(v + off);
#pragma unroll
    for (int q = 0; q < 4; ++q) {
      const float kt = (float)k4[q];
      A[q] = ed[q] * A[q] + kt * (float)v4[q];
      Bv[q] = ed[q] * Bv[q] + kt;
    }
  }
  const size_t sidx = (((size_t)b * 32 + j) << 10) + c;
  f32x4 oA = { A[0], A[1], A[2], A[3] };
  f32x4 oB = { Bv[0], Bv[1], Bv[2], Bv[3] };
  *(f32x4*)(scA + sidx) = oA;
  *(f32x4*)(scB + sidx) = oB;
}

__global__ __launch_bounds__(256) void wkv_scan(const float* __restrict__ td,
    float* __restrict__ scA, float* __restrict__ scB) {
  const int gid = blockIdx.x * 256 + threadIdx.x;   // 2048 = b*256 + c4
  const int c = (gid & 255) * 4;
  const int b = gid >> 8;
  float edL[4], a[4] = {}, bb[4] = {};
#pragma unroll
  for (int q = 0; q < 4; ++q) edL[q] = expf(-expf(td[c + q]) * 64.0f);
  size_t off = ((size_t)b << 15) + c;
  for (int j = 0; j < 32; ++j, off += 1024) {
    f32x4 Aj = *(const f32x4*)(scA + off);
    f32x4 Bj = *(const f32x4*)(scB + off);
    f32x4 ca = { a[0], a[1], a[2], a[3] };
    f32x4 cb = { bb[0], bb[1], bb[2], bb[3] };
    *(f32x4*)(scA + off) = ca;       // carry INTO chunk j
    *(f32x4*)(scB + off) = cb;
#pragma unroll
    for (int q = 0; q < 4; ++q) {
      a[q] = edL[q] * a[q] + Aj[q];
      bb[q] = edL[q] * bb[q] + Bj[q];
    }
  }
}

__global__ __launch_bounds__(256) void wkv_apply(const __bf16* __restrict__ k,
    const __bf16* __restrict__ v, const __bf16* __restrict__ sr,
    const float* __restrict__ td, const float* __restrict__ tf,
    const float* __restrict__ scA, const float* __restrict__ scB,
    __bf16* __restrict__ srw) {
  const int gid = blockIdx.x * 256 + threadIdx.x;   // b*8192 + j*256 + c4
  const int c = (gid & 255) * 4;
  const int j = (gid >> 8) & 31;
  const int b = gid >> 13;
  float ed[4], eu[4], a[4], bb[4];
#pragma unroll
  for (int q = 0; q < 4; ++q) { ed[q] = expf(-expf(td[c + q])); eu[q] = expf(tf[c + q]); }
  const size_t sidx = (((size_t)b * 32 + j) << 10) + c;
  f32x4 ca = *(const f32x4*)(scA + sidx);
  f32x4 cb = *(const f32x4*)(scB + sidx);
#pragma unroll
  for (int q = 0; q < 4; ++q) { a[q] = ca[q]; bb[q] = cb[q]; }
  size_t off = ((size_t)(b * 2048 + j * 64) << 10) + c;
  for (int i = 0; i < 64; ++i, off += 1024) {
    bf16x4 k4 = *(const bf16x4*)(k + off);
    bf16x4 v4 = *(const bf16x4*)(v + off);
    bf16x4 s4 = *(const bf16x4*)(sr + off);
    bf16x4 o4;
#pragma unroll
    for (int q = 0; q < 4; ++q) {
      const float kt = (float)k4[q];
      const float kv = kt * (float)v4[q];
      const float y = (a[q] + eu[q] * kv) / (bb[q] + eu[q] * kt);
      o4[q] = (__bf16)((float)s4[q] * y);
      a[q] = ed[q] * a[q] + kv;
      bb[q] = ed[q] * bb[q] + kt;
    }
    *(bf16x4*)(srw + off) = o4;
  }
}

// ---------------- 256x256 4-phase bf16 GEMM (R5 structure, best measured) ----------------
enum { EPI_RESID = 0, EPI_FINAL, EPI_KVR, EPI_FKR };

#define SBAR() { __builtin_amdgcn_s_barrier(); __builtin_amdgcn_sched_barrier(0); }
#define WAITL0() { asm volatile("s_waitcnt lgkmcnt(0)" ::: "memory"); __builtin_amdgcn_sched_barrier(0); }
#define VMW(n) { asm volatile("s_waitcnt vmcnt(" #n ")" ::: "memory"); __builtin_amdgcn_sched_barrier(0); }

template <int EPI>
__global__ __launch_bounds__(512, 2) void gemm8p(
    const __bf16* __restrict__ A, const __bf16* __restrict__ W,
    void* outp, const void* res, const void* sig, const int N, const int K) {
  __shared__ __bf16 sA[2][16384];   // [buf][256 rows][64 cols], row = 128 B
  __shared__ __bf16 sB[2][16384];
  const int tid = threadIdx.x;
  const int w = tid >> 6, l = tid & 63;
  const int wm = w >> 2, wn = w & 3;

  const int nwg = gridDim.x * gridDim.y;
  int wg = blockIdx.y * gridDim.x + blockIdx.x;
  wg = (wg & 7) * (nwg >> 3) + (wg >> 3);
  const int m0 = (wg / gridDim.x) << 8;
  const int n0 = (wg % gridDim.x) << 8;

  const int lr = l >> 3;
  const int lc = (l & 7) ^ lr;
  const size_t gA = (size_t)(m0 + w * 8 + lr) * K + lc * 8;
  const size_t gB = (size_t)(n0 + wn * 64 + wm * 8 + lr) * K + lc * 8;
  const int ldsA = w * 512;
  const int ldsB = (wn * 64 + wm * 8) * 64;

  const int NTK = K >> 6;

#define STAGE_A(buf, kt, i) glds16(A + gA + (size_t)(i) * 64 * K + (size_t)(kt) * 64, &sA[buf][ldsA + (i) * 4096])
#define STAGE_B(buf, kt, j) glds16(W + gB + (size_t)(j) * 16 * K + (size_t)(kt) * 64, &sB[buf][ldsB + (j) * 1024])

  const int rA = (wm * 128 + (l & 15)) * 64;
  const int rB = (wn * 64 + (l & 15)) * 64;
  const int csw = l & 7;
  const int k0 = l >> 4;
#define LDA(buf, mi, kk) (*(const bf16x8*)&sA[buf][rA + (mi) * 1024 + ((((kk) * 4 + k0) ^ csw) << 3)])
#define LDB(buf, ni, kk) (*(const bf16x8*)&sB[buf][rB + (ni) * 1024 + ((((kk) * 4 + k0) ^ csw) << 3)])

  f32x4 acc[8][4] = {};
  bf16x8 afr[8], b0[4], b1[4];

  STAGE_B(0, 0, 0); STAGE_B(0, 0, 1); STAGE_A(0, 0, 0); STAGE_A(0, 0, 2);
  STAGE_B(0, 0, 2); STAGE_B(0, 0, 3); STAGE_A(0, 0, 1); STAGE_A(0, 0, 3);

  for (int kt = 0; kt < NTK; ++kt) {
    const int buf = kt & 1, nb = buf ^ 1;
    const bool st = (kt + 1 < NTK);
    // ======== phase 0: Q(mi0-3, ni0-1) ========
    VMW(4); SBAR();
#pragma unroll
    for (int mi = 0; mi < 4; ++mi) {
      afr[mi * 2 + 0] = LDA(buf, mi, 0);
      afr[mi * 2 + 1] = LDA(buf, mi, 1);
    }
#pragma unroll
    for (int ni = 0; ni < 2; ++ni) {
      b0[ni * 2 + 0] = LDB(buf, ni, 0);
      b0[ni * 2 + 1] = LDB(buf, ni, 1);
    }
    if (st) { STAGE_B(nb, kt + 1, 0); STAGE_B(nb, kt + 1, 1); }
    WAITL0();
    __builtin_amdgcn_s_setprio(1);
#pragma unroll
    for (int mi = 0; mi < 4; ++mi)
#pragma unroll
      for (int ni = 0; ni < 2; ++ni)
#pragma unroll
        for (int kk = 0; kk < 2; ++kk)
          acc[mi][ni] = __builtin_amdgcn_mfma_f32_16x16x32_bf16(afr[mi*2+kk], b0[ni*2+kk], acc[mi][ni], 0, 0, 0);
    __builtin_amdgcn_s_setprio(0);
    // ======== phase 1: Q(mi0-3, ni2-3) ========
    if (st) { VMW(4); } else { VMW(2); }
    SBAR();
#pragma unroll
    for (int ni = 0; ni < 2; ++ni) {
      b1[ni * 2 + 0] = LDB(buf, ni + 2, 0);
      b1[ni * 2 + 1] = LDB(buf, ni + 2, 1);
    }
    if (st) { STAGE_A(nb, kt + 1, 0); STAGE_A(nb, kt + 1, 2); }
    WAITL0();
    __builtin_amdgcn_s_setprio(1);
#pragma unroll
    for (int mi = 0; mi < 4; ++mi)
#pragma unroll
      for (int ni = 0; ni < 2; ++ni)
#pragma unroll
        for (int kk = 0; kk < 2; ++kk)
          acc[mi][ni + 2] = __builtin_amdgcn_mfma_f32_16x16x32_bf16(afr[mi*2+kk], b1[ni*2+kk], acc[mi][ni + 2], 0, 0, 0);
    __builtin_amdgcn_s_setprio(0);
    // ======== phase 2: Q(mi4-7, ni0-1) ========
    if (st) { VMW(4); } else { VMW(0); }
    SBAR();
#pragma unroll
    for (int mi = 0; mi < 4; ++mi) {
      afr[mi * 2 + 0] = LDA(buf, mi + 4, 0);
      afr[mi * 2 + 1] = LDA(buf, mi + 4, 1);
    }
    if (st) { STAGE_B(nb, kt + 1, 2); STAGE_B(nb, kt + 1, 3); }
    WAITL0();
    __builtin_amdgcn_s_setprio(1);
#pragma unroll
    for (int mi = 0; mi < 4; ++mi)
#pragma unroll
      for (int ni = 0; ni < 2; ++ni)
#pragma unroll
        for (int kk = 0; kk < 2; ++kk)
          acc[mi + 4][ni] = __builtin_amdgcn_mfma_f32_16x16x32_bf16(afr[mi*2+kk], b0[ni*2+kk], acc[mi + 4][ni], 0, 0, 0);
    __builtin_amdgcn_s_setprio(0);
    // ======== phase 3: Q(mi4-7, ni2-3) ========
    if (st) { STAGE_A(nb, kt + 1, 1); STAGE_A(nb, kt + 1, 3); }
    __builtin_amdgcn_s_setprio(1);
#pragma unroll
    for (int mi = 0; mi < 4; ++mi)
#pragma unroll
      for (int ni = 0; ni < 2; ++ni)
#pragma unroll
        for (int kk = 0; kk < 2; ++kk)
          acc[mi + 4][ni + 2] = __builtin_amdgcn_mfma_f32_16x16x32_bf16(afr[mi*2+kk], b1[ni*2+kk], acc[mi + 4][ni + 2], 0, 0, 0);
    __builtin_amdgcn_s_setprio(0);
  }

  // ---- epilogue: C/D map col=lane&15, row=(lane>>4)*4+reg ----
  const int rl = (l >> 4) << 2, cl = l & 15;
#pragma unroll
  for (int mi = 0; mi < 8; ++mi) {
#pragma unroll
    for (int ni = 0; ni < 4; ++ni) {
#pragma unroll
      for (int e = 0; e < 4; ++e) {
        const int r = m0 + (wm << 7) + mi * 16 + rl + e;
        const int cidx = n0 + (wn << 6) + ni * 16 + cl;
        const float vacc = acc[mi][ni][e];
        if constexpr (EPI == EPI_RESID) {
          const size_t idx = (size_t)r * 1024 + cidx;
          ((__bf16*)outp)[idx] = (__bf16)(vacc + (float)((const __bf16*)res)[idx]);
        } else if constexpr (EPI == EPI_FINAL) {
          const size_t idx = (size_t)r * 1024 + cidx;
          ((float*)outp)[idx] = ((const float*)res)[idx] + (float)((const __bf16*)sig)[idx] * vacc;
        } else if constexpr (EPI == EPI_KVR) {
          const int sel = cidx >> 10;               // wave-uniform
          const size_t oidx = (size_t)r * 1024 + (cidx & 1023);
          if (sel == 0)      ((__bf16*)outp)[oidx] = (__bf16)expf(fminf(vacc, 60.0f));
          else if (sel == 1) ((__bf16*)const_cast<void*>(res))[oidx] = (__bf16)vacc;
          else               ((__bf16*)const_cast<void*>(sig))[oidx] = (__bf16)(1.0f / (1.0f + expf(-vacc)));
        } else {  // EPI_FKR: cidx<4096 -> kk = relu^2; else sr2 = sigmoid
          if ((cidx >> 12) == 0) {
            const float rv = fmaxf(vacc, 0.0f);
            ((__bf16*)outp)[(size_t)r * 4096 + cidx] = (__bf16)(rv * rv);
          } else {
            ((__bf16*)const_cast<void*>(sig))[(size_t)r * 1024 + (cidx - 4096)] =
                (__bf16)(1.0f / (1.0f + expf(-vacc)));
          }
        }
      }
    }
  }
}

// ---------------- launch ----------------
extern "C" void kernel_launch(void* const* d_in, const int* in_sizes, int n_in,
                              void* d_out, int out_size, void* d_ws, size_t ws_size,
                              hipStream_t stream) {
  (void)in_sizes; (void)n_in; (void)out_size;
  const float* x    = (const float*)d_in[0];
  const float* ln1g = (const float*)d_in[1];
  const float* ln1b = (const float*)d_in[2];
  const float* ln2g = (const float*)d_in[3];
  const float* ln2b = (const float*)d_in[4];
  const float* atm  = (const float*)d_in[5];
  const float* acm  = (const float*)d_in[6];
  const float* td   = (const float*)d_in[7];
  const float* tf   = (const float*)d_in[8];
  const float* Wk   = (const float*)d_in[9];
  const float* Wv   = (const float*)d_in[10];
  const float* Wr   = (const float*)d_in[11];
  const float* Wo   = (const float*)d_in[12];
  const float* ftm  = (const float*)d_in[13];
  const float* fcm  = (const float*)d_in[14];
  const float* Fk   = (const float*)d_in[15];
  const float* Fv   = (const float*)d_in[16];
  const float* Fr   = (const float*)d_in[17];

  // ---- workspace layout (dst order matches cvt_all: Wk|Wv|Wr|Wo|Fk|Fr|Fv) ----
  char* p = (char*)d_ws;
  auto takeb = [&](size_t elems) { __bf16* q = (__bf16*)p; p += elems * 2; return q; };
  __bf16* wKVR = takeb(3 * CC);   // [Wk; Wv; Wr] -> (3072, 1024)
  __bf16* wWo  = takeb(CC);
  __bf16* wFKR = takeb(CH + CC);  // [Fk; Fr] -> (5120, 1024) fused FFN B
  __bf16* wFv  = takeb(CH);
  __bf16* Ab   = takeb(NTC);      // x1 -> x2 (in-place residual)
  __bf16* Bb   = takeb(NTC);      // xm -> srw -> sr2
  __bf16* Db   = takeb(NTC);      // v  -> xm2
  float* scA = (float*)p; p += Bs * 32 * C * 4;   // wkv carries (b,j,c)
  float* scB = (float*)p; p += Bs * 32 * C * 4;
  __bf16* kk = (__bf16*)p;        // k lives here too (dead before FKR writes kk)
  const size_t used = (size_t)(p - (char*)d_ws);
  const size_t kkcap = ws_size > used ? ws_size - used : 0;
  int chunks = 4;
  if (kkcap >= NT * H * 2)          chunks = 1;
  else if (kkcap >= NT * H)         chunks = 2;
  __bf16* Cb = kk;                 // k buffer aliases kk region
  __bf16* sr  = (__bf16*)d_out;    // sigmoid(r) borrows d_out until ln2 overwrites it
  float*  x3  = (float*)d_out;

  const dim3 blk(256), blkG(512);

  // weights -> bf16, one launch (regions [Wk|Wv|Wr|Wo|Fk|Fr|Fv])
  cvt_all<<<dim3((unsigned)((5 * CC + 2 * CH) / 4 / 256)), blk, 0, stream>>>(
      Wk, Wv, Wr, Wo, Fk, Fr, Fv, wKVR);

  // x1 = ln1(x)            [Ab]
  ln_kernel<float, __bf16><<<dim3((unsigned)NT), blk, 0, stream>>>(x, ln1g, ln1b, Ab);
  // xm = mix(x1)           [Bb]
  mix_kernel<__bf16><<<dim3((unsigned)(NTC / 1024)), blk, 0, stream>>>(Ab, atm, acm, Bb);
  // fused: k=exp(min(.,60)) [Cb], v [Db], sigmoid(r) [sr]
  gemm8p<EPI_KVR><<<dim3(12, 64), blkG, 0, stream>>>(Bb, wKVR, Cb, Db, sr, 3072, 1024);
  // wkv: chunk partials -> carry scan -> apply (srw = sigmoid(r)*y into Bb)
  wkv_part<<<dim3(256), blk, 0, stream>>>(Cb, Db, td, scA, scB);
  wkv_scan<<<dim3(8), blk, 0, stream>>>(td, scA, scB);
  wkv_apply<<<dim3(256), blk, 0, stream>>>(Cb, Db, sr, td, tf, scA, scB, Bb);
  // x2 = x1 + srw@Wo^T     [Ab in-place]
  gemm8p<EPI_RESID><<<dim3(4, 64), blkG, 0, stream>>>(Bb, wWo, Ab, Ab, nullptr, 1024, 1024);
  // x3 = ln2(x2)           [d_out, fp32]
  ln_kernel<__bf16, float><<<dim3((unsigned)NT), blk, 0, stream>>>(Ab, ln2g, ln2b, x3);
  // xm2 = mix(x3)          [Db]
  mix_kernel<float><<<dim3((unsigned)(NTC / 1024)), blk, 0, stream>>>(x3, ftm, fcm, Db);
  // FFN fused per chunk: {kk = relu(xm2@Fk^T)^2, sr2 = sigmoid(xm2@Fr^T) [Bb]};
  // then out = x3 + sr2 * (kk@Fv^T)  (in-place on d_out)
  const size_t Mc = NT / chunks;
  for (int ch = 0; ch < chunks; ++ch) {
    const size_t ro = (size_t)ch * Mc;
    gemm8p<EPI_FKR><<<dim3(20, (unsigned)(Mc / 256)), blkG, 0, stream>>>(
        Db + ro * C, wFKR, kk, nullptr, Bb + ro * C, 5120, 1024);
    gemm8p<EPI_FINAL><<<dim3(4, (unsigned)(Mc / 256)), blkG, 0, stream>>>(
        kk, wFv, (float*)d_out + ro * C, (const float*)d_out + ro * C,
        Bb + ro * C, 1024, 4096);
  }
}

// Round 14
// 715.262 us; speedup vs baseline: 1.1161x; 1.0294x over previous
//
#include <hip/hip_runtime.h>
#include <hip/hip_bf16.h>

typedef float f32x4 __attribute__((ext_vector_type(4)));
typedef __bf16 bf16x8 __attribute__((ext_vector_type(8)));
typedef __bf16 bf16x4 __attribute__((ext_vector_type(4)));

#define DEVI static __device__ __forceinline__

DEVI void glds16(const void* g, void* l) {
  __builtin_amdgcn_global_load_lds((__attribute__((address_space(1))) void*)g,
                                   (__attribute__((address_space(3))) void*)l, 16, 0, 0);
}

DEVI f32x4 load4(const float* p) { return *(const f32x4*)p; }
DEVI f32x4 load4(const __bf16* p) {
  bf16x4 v = *(const bf16x4*)p;
  f32x4 o = { (float)v[0], (float)v[1], (float)v[2], (float)v[3] };
  return o;
}
DEVI void store4(float* p, f32x4 v) { *(f32x4*)p = v; }
DEVI void store4(__bf16* p, f32x4 v) {
  bf16x4 o = { (__bf16)v[0], (__bf16)v[1], (__bf16)v[2], (__bf16)v[3] };
  *(bf16x4*)p = o;
}

constexpr size_t C = 1024, T = 2048, Bs = 8, H = 4096;
constexpr size_t NT = Bs * T;        // 16384 tokens
constexpr size_t NTC = NT * C;       // 16M elems
constexpr size_t CC = C * C;
constexpr size_t CH = C * H;

// ---------------- all weights fp32 -> bf16, one launch ----------------
// dst region order: [Wk|Wv|Wr | Wo | Fk | Fv | Fr]
__global__ __launch_bounds__(256) void cvt_all(
    const float* __restrict__ Wk, const float* __restrict__ Wv,
    const float* __restrict__ Wr, const float* __restrict__ Wo,
    const float* __restrict__ Fk, const float* __restrict__ Fv,
    const float* __restrict__ Fr, __bf16* __restrict__ out) {
  const size_t e = ((size_t)blockIdx.x * 256 + threadIdx.x) * 4;
  const float* src; size_t rel;
  if      (e < CC)                   { src = Wk; rel = e; }
  else if (e < 2 * CC)               { src = Wv; rel = e - CC; }
  else if (e < 3 * CC)               { src = Wr; rel = e - 2 * CC; }
  else if (e < 4 * CC)               { src = Wo; rel = e - 3 * CC; }
  else if (e < 4 * CC + CH)          { src = Fk; rel = e - 4 * CC; }
  else if (e < 4 * CC + 2 * CH)      { src = Fv; rel = e - 4 * CC - CH; }
  else                               { src = Fr; rel = e - 4 * CC - 2 * CH; }
  f32x4 v = *(const f32x4*)(src + rel);
  store4(out + e, v);
}

// ---------------- LayerNorm over C=1024, one block per token ----------------
template <typename TIN, typename TOUT>
__global__ __launch_bounds__(256) void ln_kernel(const TIN* __restrict__ x,
    const float* __restrict__ gw, const float* __restrict__ bw,
    TOUT* __restrict__ out) {
  const size_t row = blockIdx.x;
  f32x4 v = load4(x + row * 1024 + threadIdx.x * 4);
  float s = v[0] + v[1] + v[2] + v[3];
  float q = v[0]*v[0] + v[1]*v[1] + v[2]*v[2] + v[3]*v[3];
#pragma unroll
  for (int o = 32; o > 0; o >>= 1) { s += __shfl_down(s, o); q += __shfl_down(q, o); }
  __shared__ float ss[4], qq[4];
  const int w = threadIdx.x >> 6, l = threadIdx.x & 63;
  if (l == 0) { ss[w] = s; qq[w] = q; }
  __syncthreads();
  s = ss[0] + ss[1] + ss[2] + ss[3];
  q = qq[0] + qq[1] + qq[2] + qq[3];
  const float mean = s * (1.0f / 1024.0f);
  const float var = q * (1.0f / 1024.0f) - mean * mean;
  const float rstd = rsqrtf(var + 1e-5f);
  f32x4 g4 = *(const f32x4*)(gw + threadIdx.x * 4);
  f32x4 b4 = *(const f32x4*)(bw + threadIdx.x * 4);
  f32x4 o;
#pragma unroll
  for (int j = 0; j < 4; ++j) o[j] = (v[j] - mean) * rstd * g4[j] + b4[j];
  store4(out + row * 1024 + threadIdx.x * 4, o);
}

// ---------------- time-shift mix -> bf16 ----------------
template <typename TIN>
__global__ __launch_bounds__(256) void mix_kernel(const TIN* __restrict__ x,
    const float* __restrict__ tm, const float* __restrict__ cm,
    __bf16* __restrict__ out) {
  const int idx = blockIdx.x * 256 + threadIdx.x;   // over B*T*C/4
  const int t = (idx >> 8) & 2047;                   // T=2048
  const int c = (idx & 255) * 4;                     // C/4=256
  const size_t base = ((size_t)(idx >> 8) << 10) + c;
  f32x4 xv = load4(x + base);
  f32x4 xm1 = {0.f, 0.f, 0.f, 0.f}, xp1 = {0.f, 0.f, 0.f, 0.f};
  if (t > 0)    xm1 = load4(x + base - 1024);
  if (t < 2047) xp1 = load4(x + base + 1024);
  f32x4 tm4 = *(const f32x4*)(tm + c);
  f32x4 cm4 = *(const f32x4*)(cm + c);
  f32x4 xc = (c < 512) ? xm1 : xp1;
  f32x4 o;
#pragma unroll
  for (int j = 0; j < 4; ++j)
    o[j] = xv[j] * tm4[j] + xm1[j] * (1.0f - tm4[j]) + xc[j] * cm4[j];
  store4(out + base, o);
}

// ---------------- WKV chunk-parallel scan, x4 vectorized (exact regroup) ----------------
__global__ __launch_bounds__(256) void wkv_part(const __bf16* __restrict__ k,
    const __bf16* __restrict__ v, const float* __restrict__ td,
    float* __restrict__ scA, float* __restrict__ scB) {
  const int gid = blockIdx.x * 256 + threadIdx.x;   // b*8192 + j*256 + c4
  const int c = (gid & 255) * 4;
  const int j = (gid >> 8) & 31;
  const int b = gid >> 13;
  float ed[4], A[4] = {}, Bv[4] = {};
#pragma unroll
  for (int q = 0; q < 4; ++q) ed[q] = expf(-expf(td[c + q]));
  size_t off = ((size_t)(b * 2048 + j * 64) << 10) + c;
  for (int i = 0; i < 64; ++i, off += 1024) {
    bf16x4 k4 = *(const bf16x4*)(k + off);
    bf16x4 v4 = *(const bf16x4*)(v + off);
#pragma unroll
    for (int q = 0; q < 4; ++q) {
      const float kt = (float)k4[q];
      A[q] = ed[q] * A[q] + kt * (float)v4[q];
      Bv[q] = ed[q] * Bv[q] + kt;
    }
  }
  const size_t sidx = (((size_t)b * 32 + j) << 10) + c;
  f32x4 oA = { A[0], A[1], A[2], A[3] };
  f32x4 oB = { Bv[0], Bv[1], Bv[2], Bv[3] };
  *(f32x4*)(scA + sidx) = oA;
  *(f32x4*)(scB + sidx) = oB;
}

__global__ __launch_bounds__(256) void wkv_scan(const float* __restrict__ td,
    float* __restrict__ scA, float* __restrict__ scB) {
  const int gid = blockIdx.x * 256 + threadIdx.x;   // 2048 = b*256 + c4
  const int c = (gid & 255) * 4;
  const int b = gid >> 8;
  float edL[4], a[4] = {}, bb[4] = {};
#pragma unroll
  for (int q = 0; q < 4; ++q) edL[q] = expf(-expf(td[c + q]) * 64.0f);
  size_t off = ((size_t)b << 15) + c;
  for (int j = 0; j < 32; ++j, off += 1024) {
    f32x4 Aj = *(const f32x4*)(scA + off);
    f32x4 Bj = *(const f32x4*)(scB + off);
    f32x4 ca = { a[0], a[1], a[2], a[3] };
    f32x4 cb = { bb[0], bb[1], bb[2], bb[3] };
    *(f32x4*)(scA + off) = ca;       // carry INTO chunk j
    *(f32x4*)(scB + off) = cb;
#pragma unroll
    for (int q = 0; q < 4; ++q) {
      a[q] = edL[q] * a[q] + Aj[q];
      bb[q] = edL[q] * bb[q] + Bj[q];
    }
  }
}

__global__ __launch_bounds__(256) void wkv_apply(const __bf16* __restrict__ k,
    const __bf16* __restrict__ v, const __bf16* __restrict__ sr,
    const float* __restrict__ td, const float* __restrict__ tf,
    const float* __restrict__ scA, const float* __restrict__ scB,
    __bf16* __restrict__ srw) {
  const int gid = blockIdx.x * 256 + threadIdx.x;   // b*8192 + j*256 + c4
  const int c = (gid & 255) * 4;
  const int j = (gid >> 8) & 31;
  const int b = gid >> 13;
  float ed[4], eu[4], a[4], bb[4];
#pragma unroll
  for (int q = 0; q < 4; ++q) { ed[q] = expf(-expf(td[c + q])); eu[q] = expf(tf[c + q]); }
  const size_t sidx = (((size_t)b * 32 + j) << 10) + c;
  f32x4 ca = *(const f32x4*)(scA + sidx);
  f32x4 cb = *(const f32x4*)(scB + sidx);
#pragma unroll
  for (int q = 0; q < 4; ++q) { a[q] = ca[q]; bb[q] = cb[q]; }
  size_t off = ((size_t)(b * 2048 + j * 64) << 10) + c;
  for (int i = 0; i < 64; ++i, off += 1024) {
    bf16x4 k4 = *(const bf16x4*)(k + off);
    bf16x4 v4 = *(const bf16x4*)(v + off);
    bf16x4 s4 = *(const bf16x4*)(sr + off);
    bf16x4 o4;
#pragma unroll
    for (int q = 0; q < 4; ++q) {
      const float kt = (float)k4[q];
      const float kv = kt * (float)v4[q];
      const float y = (a[q] + eu[q] * kv) / (bb[q] + eu[q] * kt);
      o4[q] = (__bf16)((float)s4[q] * y);
      a[q] = ed[q] * a[q] + kv;
      bb[q] = ed[q] * bb[q] + kt;
    }
    *(bf16x4*)(srw + off) = o4;
  }
}

// ---------------- 256x256 4-phase bf16 GEMM (R5 structure, best measured) ----------------
// out[m,n] = sum_k A[m,k]*W[n,k].  8 waves (2Mx4N), BK=64, dbuf LDS (128 KiB),
// 1 barrier/phase, counted vmcnt, 128-B-row XOR swizzle (0-conflict verified),
// setprio around MFMA clusters, bijective XCD swizzle.
enum { EPI_NONE = 0, EPI_EXP, EPI_SIG, EPI_RELU2, EPI_RESID, EPI_FINAL, EPI_KVR };

#define SBAR() { __builtin_amdgcn_s_barrier(); __builtin_amdgcn_sched_barrier(0); }
#define WAITL0() { asm volatile("s_waitcnt lgkmcnt(0)" ::: "memory"); __builtin_amdgcn_sched_barrier(0); }
#define VMW(n) { asm volatile("s_waitcnt vmcnt(" #n ")" ::: "memory"); __builtin_amdgcn_sched_barrier(0); }

template <int EPI>
__global__ __launch_bounds__(512, 2) void gemm8p(
    const __bf16* __restrict__ A, const __bf16* __restrict__ W,
    void* outp, const void* res, const void* sig, const int N, const int K) {
  __shared__ __bf16 sA[2][16384];   // [buf][256 rows][64 cols], row = 128 B
  __shared__ __bf16 sB[2][16384];
  const int tid = threadIdx.x;
  const int w = tid >> 6, l = tid & 63;
  const int wm = w >> 2, wn = w & 3;

  // bijective XCD swizzle (all grids have nwg % 8 == 0)
  const int nwg = gridDim.x * gridDim.y;
  int wg = blockIdx.y * gridDim.x + blockIdx.x;
  wg = (wg & 7) * (nwg >> 3) + (wg >> 3);
  const int m0 = (wg / gridDim.x) << 8;
  const int n0 = (wg % gridDim.x) << 8;

  // ---- staging (global -> LDS, linear dest, pre-swizzled source) ----
  const int lr = l >> 3;
  const int lc = (l & 7) ^ lr;
  const size_t gA = (size_t)(m0 + w * 8 + lr) * K + lc * 8;            // A issue i: +i*64 rows
  const size_t gB = (size_t)(n0 + wn * 64 + wm * 8 + lr) * K + lc * 8; // B issue j: +j*16 rows
  const int ldsA = w * 512;
  const int ldsB = (wn * 64 + wm * 8) * 64;

  const int NTK = K >> 6;

#define STAGE_A(buf, kt, i) glds16(A + gA + (size_t)(i) * 64 * K + (size_t)(kt) * 64, &sA[buf][ldsA + (i) * 4096])
#define STAGE_B(buf, kt, j) glds16(W + gB + (size_t)(j) * 16 * K + (size_t)(kt) * 64, &sB[buf][ldsB + (j) * 1024])

  // ---- fragment reads (swizzled chunk) ----
  const int rA = (wm * 128 + (l & 15)) * 64;
  const int rB = (wn * 64 + (l & 15)) * 64;
  const int csw = l & 7;
  const int k0 = l >> 4;    // 0..3
#define LDA(buf, mi, kk) (*(const bf16x8*)&sA[buf][rA + (mi) * 1024 + ((((kk) * 4 + k0) ^ csw) << 3)])
#define LDB(buf, ni, kk) (*(const bf16x8*)&sB[buf][rB + (ni) * 1024 + ((((kk) * 4 + k0) ^ csw) << 3)])

  f32x4 acc[8][4] = {};
  bf16x8 afr[8], b0[4], b1[4];

  // prologue: stage tile 0 into buf 0, in consumption order
  STAGE_B(0, 0, 0); STAGE_B(0, 0, 1); STAGE_A(0, 0, 0); STAGE_A(0, 0, 2);
  STAGE_B(0, 0, 2); STAGE_B(0, 0, 3); STAGE_A(0, 0, 1); STAGE_A(0, 0, 3);

  for (int kt = 0; kt < NTK; ++kt) {
    const int buf = kt & 1, nb = buf ^ 1;
    const bool st = (kt + 1 < NTK);
    // ======== phase 0: Q(mi0-3, ni0-1) ========
    VMW(4); SBAR();
#pragma unroll
    for (int mi = 0; mi < 4; ++mi) {
      afr[mi * 2 + 0] = LDA(buf, mi, 0);
      afr[mi * 2 + 1] = LDA(buf, mi, 1);
    }
#pragma unroll
    for (int ni = 0; ni < 2; ++ni) {
      b0[ni * 2 + 0] = LDB(buf, ni, 0);
      b0[ni * 2 + 1] = LDB(buf, ni, 1);
    }
    if (st) { STAGE_B(nb, kt + 1, 0); STAGE_B(nb, kt + 1, 1); }
    WAITL0();
    __builtin_amdgcn_s_setprio(1);
#pragma unroll
    for (int mi = 0; mi < 4; ++mi)
#pragma unroll
      for (int ni = 0; ni < 2; ++ni)
#pragma unroll
        for (int kk = 0; kk < 2; ++kk)
          acc[mi][ni] = __builtin_amdgcn_mfma_f32_16x16x32_bf16(afr[mi*2+kk], b0[ni*2+kk], acc[mi][ni], 0, 0, 0);
    __builtin_amdgcn_s_setprio(0);
    // ======== phase 1: Q(mi0-3, ni2-3) ========
    if (st) { VMW(4); } else { VMW(2); }
    SBAR();
#pragma unroll
    for (int ni = 0; ni < 2; ++ni) {
      b1[ni * 2 + 0] = LDB(buf, ni + 2, 0);
      b1[ni * 2 + 1] = LDB(buf, ni + 2, 1);
    }
    if (st) { STAGE_A(nb, kt + 1, 0); STAGE_A(nb, kt + 1, 2); }
    WAITL0();
    __builtin_amdgcn_s_setprio(1);
#pragma unroll
    for (int mi = 0; mi < 4; ++mi)
#pragma unroll
      for (int ni = 0; ni < 2; ++ni)
#pragma unroll
        for (int kk = 0; kk < 2; ++kk)
          acc[mi][ni + 2] = __builtin_amdgcn_mfma_f32_16x16x32_bf16(afr[mi*2+kk], b1[ni*2+kk], acc[mi][ni + 2], 0, 0, 0);
    __builtin_amdgcn_s_setprio(0);
    // ======== phase 2: Q(mi4-7, ni0-1) ========
    if (st) { VMW(4); } else { VMW(0); }
    SBAR();
#pragma unroll
    for (int mi = 0; mi < 4; ++mi) {
      afr[mi * 2 + 0] = LDA(buf, mi + 4, 0);
      afr[mi * 2 + 1] = LDA(buf, mi + 4, 1);
    }
    if (st) { STAGE_B(nb, kt + 1, 2); STAGE_B(nb, kt + 1, 3); }
    WAITL0();
    __builtin_amdgcn_s_setprio(1);
#pragma unroll
    for (int mi = 0; mi < 4; ++mi)
#pragma unroll
      for (int ni = 0; ni < 2; ++ni)
#pragma unroll
        for (int kk = 0; kk < 2; ++kk)
          acc[mi + 4][ni] = __builtin_amdgcn_mfma_f32_16x16x32_bf16(afr[mi*2+kk], b0[ni*2+kk], acc[mi + 4][ni], 0, 0, 0);
    __builtin_amdgcn_s_setprio(0);
    // ======== phase 3: Q(mi4-7, ni2-3) ======== (no reads, no barrier)
    if (st) { STAGE_A(nb, kt + 1, 1); STAGE_A(nb, kt + 1, 3); }
    __builtin_amdgcn_s_setprio(1);
#pragma unroll
    for (int mi = 0; mi < 4; ++mi)
#pragma unroll
      for (int ni = 0; ni < 2; ++ni)
#pragma unroll
        for (int kk = 0; kk < 2; ++kk)
          acc[mi + 4][ni + 2] = __builtin_amdgcn_mfma_f32_16x16x32_bf16(afr[mi*2+kk], b1[ni*2+kk], acc[mi + 4][ni + 2], 0, 0, 0);
    __builtin_amdgcn_s_setprio(0);
  }

  // ---- epilogue: C/D map col=lane&15, row=(lane>>4)*4+reg ----
  const int rl = (l >> 4) << 2, cl = l & 15;
#pragma unroll
  for (int mi = 0; mi < 8; ++mi) {
#pragma unroll
    for (int ni = 0; ni < 4; ++ni) {
#pragma unroll
      for (int e = 0; e < 4; ++e) {
        const int r = m0 + (wm << 7) + mi * 16 + rl + e;
        const int cidx = n0 + (wn << 6) + ni * 16 + cl;
        const size_t idx = (size_t)r * N + cidx;
        const float vacc = acc[mi][ni][e];
        if constexpr (EPI == EPI_NONE) {
          ((__bf16*)outp)[idx] = (__bf16)vacc;
        } else if constexpr (EPI == EPI_EXP) {
          ((__bf16*)outp)[idx] = (__bf16)expf(fminf(vacc, 60.0f));
        } else if constexpr (EPI == EPI_SIG) {
          ((__bf16*)outp)[idx] = (__bf16)(1.0f / (1.0f + expf(-vacc)));
        } else if constexpr (EPI == EPI_RELU2) {
          const float rv = fmaxf(vacc, 0.0f);
          ((__bf16*)outp)[idx] = (__bf16)(rv * rv);
        } else if constexpr (EPI == EPI_RESID) {
          ((__bf16*)outp)[idx] = (__bf16)(vacc + (float)((const __bf16*)res)[idx]);
        } else if constexpr (EPI == EPI_FINAL) {
          ((float*)outp)[idx] = ((const float*)res)[idx] + (float)((const __bf16*)sig)[idx] * vacc;
        } else {  // EPI_KVR: col block 0 -> k=exp(clamp), 1 -> v, 2 -> sigmoid(r)
          const int sel = cidx >> 10;               // wave-uniform
          const size_t oidx = (size_t)r * 1024 + (cidx & 1023);
          if (sel == 0)      ((__bf16*)outp)[oidx] = (__bf16)expf(fminf(vacc, 60.0f));
          else if (sel == 1) ((__bf16*)const_cast<void*>(res))[oidx] = (__bf16)vacc;
          else               ((__bf16*)const_cast<void*>(sig))[oidx] = (__bf16)(1.0f / (1.0f + expf(-vacc)));
        }
      }
    }
  }
}

// ---------------- launch ----------------
extern "C" void kernel_launch(void* const* d_in, const int* in_sizes, int n_in,
                              void* d_out, int out_size, void* d_ws, size_t ws_size,
                              hipStream_t stream) {
  (void)in_sizes; (void)n_in; (void)out_size;
  const float* x    = (const float*)d_in[0];
  const float* ln1g = (const float*)d_in[1];
  const float* ln1b = (const float*)d_in[2];
  const float* ln2g = (const float*)d_in[3];
  const float* ln2b = (const float*)d_in[4];
  const float* atm  = (const float*)d_in[5];
  const float* acm  = (const float*)d_in[6];
  const float* td   = (const float*)d_in[7];
  const float* tf   = (const float*)d_in[8];
  const float* Wk   = (const float*)d_in[9];
  const float* Wv   = (const float*)d_in[10];
  const float* Wr   = (const float*)d_in[11];
  const float* Wo   = (const float*)d_in[12];
  const float* ftm  = (const float*)d_in[13];
  const float* fcm  = (const float*)d_in[14];
  const float* Fk   = (const float*)d_in[15];
  const float* Fv   = (const float*)d_in[16];
  const float* Fr   = (const float*)d_in[17];

  // ---- workspace layout (dst order matches cvt_all: Wk|Wv|Wr|Wo|Fk|Fv|Fr) ----
  char* p = (char*)d_ws;
  auto takeb = [&](size_t elems) { __bf16* q = (__bf16*)p; p += elems * 2; return q; };
  __bf16* wKVR = takeb(3 * CC);   // [Wk; Wv; Wr] -> (3072, 1024)
  __bf16* wWo  = takeb(CC);
  __bf16* wFk  = takeb(CH);
  __bf16* wFv  = takeb(CH);
  __bf16* wFr  = takeb(CC);
  __bf16* Ab   = takeb(NTC);      // x1 -> x2 (in-place residual)
  __bf16* Bb   = takeb(NTC);      // xm -> srw -> sr2
  __bf16* Db   = takeb(NTC);      // v  -> xm2
  float* scA = (float*)p; p += Bs * 32 * C * 4;   // wkv carries (b,j,c)
  float* scB = (float*)p; p += Bs * 32 * C * 4;
  __bf16* kk = (__bf16*)p;        // k lives here too (dead before Fk writes kk)
  const size_t used = (size_t)(p - (char*)d_ws);
  const size_t kkcap = ws_size > used ? ws_size - used : 0;
  int chunks = 4;
  if (kkcap >= NT * H * 2)          chunks = 1;
  else if (kkcap >= NT * H)         chunks = 2;
  __bf16* Cb = kk;                 // k buffer aliases kk region
  __bf16* sr  = (__bf16*)d_out;    // sigmoid(r) borrows d_out until ln2 overwrites it
  float*  x3  = (float*)d_out;

  const dim3 blk(256), blkG(512);

  // weights -> bf16, one launch
  cvt_all<<<dim3((unsigned)((5 * CC + 2 * CH) / 4 / 256)), blk, 0, stream>>>(
      Wk, Wv, Wr, Wo, Fk, Fv, Fr, wKVR);

  // x1 = ln1(x)            [Ab]
  ln_kernel<float, __bf16><<<dim3((unsigned)NT), blk, 0, stream>>>(x, ln1g, ln1b, Ab);
  // xm = mix(x1)           [Bb]
  mix_kernel<__bf16><<<dim3((unsigned)(NTC / 1024)), blk, 0, stream>>>(Ab, atm, acm, Bb);
  // fused: k=exp(min(.,60)) [Cb], v [Db], sigmoid(r) [sr]
  gemm8p<EPI_KVR><<<dim3(12, 64), blkG, 0, stream>>>(Bb, wKVR, Cb, Db, sr, 3072, 1024);
  // wkv: chunk partials -> carry scan -> apply (srw = sigmoid(r)*y into Bb)
  wkv_part<<<dim3(256), blk, 0, stream>>>(Cb, Db, td, scA, scB);
  wkv_scan<<<dim3(8), blk, 0, stream>>>(td, scA, scB);
  wkv_apply<<<dim3(256), blk, 0, stream>>>(Cb, Db, sr, td, tf, scA, scB, Bb);
  // x2 = x1 + srw@Wo^T     [Ab in-place]
  gemm8p<EPI_RESID><<<dim3(4, 64), blkG, 0, stream>>>(Bb, wWo, Ab, Ab, nullptr, 1024, 1024);
  // x3 = ln2(x2)           [d_out, fp32]
  ln_kernel<__bf16, float><<<dim3((unsigned)NT), blk, 0, stream>>>(Ab, ln2g, ln2b, x3);
  // xm2 = mix(x3)          [Db]
  mix_kernel<float><<<dim3((unsigned)(NTC / 1024)), blk, 0, stream>>>(x3, ftm, fcm, Db);
  // sr2 = sigmoid(xm2@Fr^T) [Bb]
  gemm8p<EPI_SIG><<<dim3(4, 64), blkG, 0, stream>>>(Db, wFr, Bb, nullptr, nullptr, 1024, 1024);
  // FFN: kk = relu(xm2@Fk^T)^2 [kk], out = x3 + sr2 * (kk@Fv^T)  (chunked if ws small)
  const size_t Mc = NT / chunks;
  for (int ch = 0; ch < chunks; ++ch) {
    const size_t ro = (size_t)ch * Mc;
    gemm8p<EPI_RELU2><<<dim3(16, (unsigned)(Mc / 256)), blkG, 0, stream>>>(
        Db + ro * C, wFk, kk, nullptr, nullptr, 4096, 1024);
    gemm8p<EPI_FINAL><<<dim3(4, (unsigned)(Mc / 256)), blkG, 0, stream>>>(
        kk, wFv, (float*)d_out + ro * C, (const float*)d_out + ro * C,
        Bb + ro * C, 1024, 4096);
  }
}